// Round 12
// baseline (61.750 us; speedup 1.0000x reference)
//
#include <hip/hip_runtime.h>

#define BATCH   8
#define HH      512
#define WW      512
#define IMGPIX  (HH * WW)          // 262144 = 1<<18
#define NPIX    (BATCH * IMGPIX)   // 2097152
#define NWORDS  (NPIX / 64)        // 32768 packed words
#define WPR     8                  // 64-bit words per 512-px row
#define FPSCALE 262144.0           // 2^18 fixed-point scale for i64 reduction
#define MAXPAIR 256

typedef unsigned long long u64;
typedef unsigned int u32;

// ---------------- kernel 1: CE loss + packed binary mask + zero accumulators ----------------
__global__ void prep_kernel(const float* __restrict__ pred, const int* __restrict__ target,
                            float* __restrict__ L, u64* __restrict__ xp,
                            u64* __restrict__ acc64, u32* __restrict__ ticket) {
    int i = blockIdx.x * blockDim.x + threadIdx.x;
    if (i == 0) { acc64[0] = 0ULL; ticket[0] = 0u; }
    if (i >= NPIX) return;
    int b = i >> 18;
    int hw = i & (IMGPIX - 1);
    float p0 = pred[((size_t)(2 * b) << 18) + hw];
    float p1 = pred[((size_t)(2 * b + 1) << 18) + hw];
    // lse = max + log(1 + exp(-|p0-p1|)); fast HW transcendentals (threshold is 1.73 abs)
    float ad = fabsf(p0 - p1);
    float lse = fmaxf(p0, p1) + __logf(1.0f + __expf(-ad));
    int t = target[i];
    L[i] = lse - (t ? p1 : p0);            // -log_softmax[target]
    u64 word = __ballot(p1 > p0);          // 64 consecutive pixels per wave
    if ((threadIdx.x & 63) == 0) xp[i >> 6] = word;
}

// ---------------- bit-sliced helpers ----------------
#define FA(a,b,c,s,cy) { u64 _x = (a)^(b); (s) = _x^(c); (cy) = ((a)&(b)) | ((c)&_x); }
#define HA(a,b,s,cy)   { (s) = (a)^(b); (cy) = (a)&(b); }

// ZS delete mask for one row (8 words) given neighbor rows U (above) and D (below).
// Pure: does NOT update M. Returns OR of per-word delete masks via *dels.
template<int FIRST>
__device__ __forceinline__ u64 zs_del(const u64* __restrict__ U, const u64* __restrict__ M,
                                      const u64* __restrict__ D, u64* __restrict__ dels)
{
    u64 ch = 0;
    #pragma unroll
    for (int k = 0; k < WPR; ++k) {
        u64 Mc = M[k];
        dels[k] = 0ULL;
        if (Mc == 0ULL) continue;
        u64 Uc = U[k], Dc = D[k];
        u64 Up = k     ? U[k-1] : 0ULL;
        u64 Mp = k     ? M[k-1] : 0ULL;
        u64 Dp = k     ? D[k-1] : 0ULL;
        u64 Un = k < 7 ? U[k+1] : 0ULL;
        u64 Mn = k < 7 ? M[k+1] : 0ULL;
        u64 Dn = k < 7 ? D[k+1] : 0ULL;
        u64 P2 = Uc, P6 = Dc;
        u64 P3 = (Uc >> 1) | (Un << 63);
        u64 P4 = (Mc >> 1) | (Mn << 63);
        u64 P5 = (Dc >> 1) | (Dn << 63);
        u64 P9 = (Uc << 1) | (Up >> 63);
        u64 P8 = (Mc << 1) | (Mp >> 63);
        u64 P7 = (Dc << 1) | (Dp >> 63);

        u64 sa,ca, sb,cb, sc,cc, b0,cd, sd,ce, b1,cf, b2,b3;
        FA(P2,P3,P4, sa,ca);
        FA(P5,P6,P7, sb,cb);
        FA(P8,P9,sa, sc,cc);
        HA(sb,sc,    b0,cd);
        FA(ca,cb,cc, sd,ce);
        HA(sd,cd,    b1,cf);
        HA(ce,cf,    b2,b3);
        u64 ge2 = b1 | b2 | b3;
        u64 le6 = ~(b3 | (b0 & b1 & b2));

        u64 e, seen, two = 0;
        seen = (~P2) & P3;
        e = (~P3) & P4; two |= seen & e; seen |= e;
        e = (~P4) & P5; two |= seen & e; seen |= e;
        e = (~P5) & P6; two |= seen & e; seen |= e;
        e = (~P6) & P7; two |= seen & e; seen |= e;
        e = (~P7) & P8; two |= seen & e; seen |= e;
        e = (~P8) & P9; two |= seen & e; seen |= e;
        e = (~P9) & P2; two |= seen & e; seen |= e;
        u64 A1 = seen & ~two;

        u64 c34;
        if (FIRST) { u64 t = P4 & P6; c34 = t & (P2 | P8); }
        else       { u64 t = P2 & P8; c34 = t & (P4 | P6); }

        u64 del = Mc & ge2 & le6 & A1 & ~c34;
        dels[k] = del;
        ch |= del;
    }
    return ch;
}

// swizzled word index into a [512][8] u64 buffer: XOR spreads row-start banks so the
// even word-stride (8) doesn't serialize (start banks cover all 16 pairs -> inherent-BW only)
__device__ __forceinline__ int sidx(int h, int k) {
    return (h << 3) + (k ^ ((h >> 1) & 7));
}

// ---------------- kernel 2: double-buffered skeletonize, 2 rows/thread ----------------
// 8 blocks x 256 threads (thread = rows 2t, 2t+1). Own rows in registers; only rows
// 2t-1 and 2t+2 come from LDS (halves ds_read issue). Both rows' substep computed
// from OLD values (no copies), then XOR-updated. 2 barriers per pair.
__global__ __launch_bounds__(256)
void skel_kernel(const u64* __restrict__ xp, u64* __restrict__ eg)
{
    __shared__ u64 buf[2][HH * WPR];       // 2 x 32 KB = 64 KB, XOR-swizzled
    const int t  = threadIdx.x;
    const int b  = blockIdx.x;
    const int r0 = 2 * t, r1 = 2 * t + 1;

    u64 M0[WPR], M1[WPR], U[WPR], D[WPR], d0[WPR], d1[WPR];
    const u64* src = xp + ((size_t)b << 12) + (size_t)r0 * WPR;
    #pragma unroll
    for (int k = 0; k < WPR; ++k) {
        M0[k] = src[k];        buf[0][sidx(r0, k)] = M0[k];
        M1[k] = src[WPR + k];  buf[0][sidx(r1, k)] = M1[k];
    }
    __syncthreads();

    const bool hasU = (r0 > 0), hasD = (r1 < HH - 1);

    for (int p = 0; p < MAXPAIR; ++p) {
        // ---- substep A: read buf0 neighbors, compute both rows from old values
        #pragma unroll
        for (int k = 0; k < WPR; ++k) {
            U[k] = hasU ? buf[0][sidx(r0 - 1, k)] : 0ULL;
            D[k] = hasD ? buf[0][sidx(r1 + 1, k)] : 0ULL;
        }
        u64 chA = zs_del<1>(U, M0, M1, d0) | zs_del<1>(M0, M1, D, d1);
        #pragma unroll
        for (int k = 0; k < WPR; ++k) {
            M0[k] ^= d0[k];  buf[1][sidx(r0, k)] = M0[k];
            M1[k] ^= d1[k];  buf[1][sidx(r1, k)] = M1[k];
        }
        __syncthreads();

        // ---- substep B: read buf1 neighbors, write buf0
        #pragma unroll
        for (int k = 0; k < WPR; ++k) {
            U[k] = hasU ? buf[1][sidx(r0 - 1, k)] : 0ULL;
            D[k] = hasD ? buf[1][sidx(r1 + 1, k)] : 0ULL;
        }
        u64 chB = zs_del<0>(U, M0, M1, d0) | zs_del<0>(M0, M1, D, d1);
        #pragma unroll
        for (int k = 0; k < WPR; ++k) {
            M0[k] ^= d0[k];  buf[0][sidx(r0, k)] = M0[k];
            M1[k] ^= d1[k];  buf[0][sidx(r1, k)] = M1[k];
        }
        if (!__syncthreads_or((chA | chB) != 0ULL)) break; // pair deleted nothing anywhere
    }

    // ---- endpoints E = skel & (exactly one 8-neighbor) for rows r0, r1
    #pragma unroll
    for (int k = 0; k < WPR; ++k) {
        U[k] = hasU ? buf[0][sidx(r0 - 1, k)] : 0ULL;
        D[k] = hasD ? buf[0][sidx(r1 + 1, k)] : 0ULL;
    }
    u64* egr = eg + ((size_t)b << 12) + (size_t)r0 * WPR;
    #pragma unroll
    for (int half = 0; half < 2; ++half) {
        const u64* Ur = half ? M0 : U;
        const u64* Mr = half ? M1 : M0;
        const u64* Dr = half ? D  : M1;
        #pragma unroll
        for (int k = 0; k < WPR; ++k) {
            u64 Mc = Mr[k];
            u64 Uc = Ur[k], Dc = Dr[k];
            u64 Up = k     ? Ur[k-1] : 0ULL;
            u64 Mp = k     ? Mr[k-1] : 0ULL;
            u64 Dp = k     ? Dr[k-1] : 0ULL;
            u64 Un = k < 7 ? Ur[k+1] : 0ULL;
            u64 Mn = k < 7 ? Mr[k+1] : 0ULL;
            u64 Dn = k < 7 ? Dr[k+1] : 0ULL;
            u64 P2 = Uc, P6 = Dc;
            u64 P3 = (Uc >> 1) | (Un << 63);
            u64 P4 = (Mc >> 1) | (Mn << 63);
            u64 P5 = (Dc >> 1) | (Dn << 63);
            u64 P9 = (Uc << 1) | (Up >> 63);
            u64 P8 = (Mc << 1) | (Mp >> 63);
            u64 P7 = (Dc << 1) | (Dp >> 63);
            u64 e, seen, two = 0;
            seen = P2;
            e = P3; two |= seen & e; seen |= e;
            e = P4; two |= seen & e; seen |= e;
            e = P5; two |= seen & e; seen |= e;
            e = P6; two |= seen & e; seen |= e;
            e = P7; two |= seen & e; seen |= e;
            e = P8; two |= seen & e; seen |= e;
            e = P9; two |= seen & e; seen |= e;
            egr[half * WPR + k] = Mc & seen & ~two;   // exactly one neighbor
        }
    }
}

// ---------------- packed 9x9 count helpers ----------------
struct Planes { u64 p0, p1, p2, p3; };

__device__ __forceinline__ Planes vcount9(const u64 r[9]) {
    u64 s0,c0, s1,c1, s2,c2, p0,t0, t1,t2, p1,t3, p2,p3;
    FA(r[0],r[1],r[2], s0,c0);
    FA(r[3],r[4],r[5], s1,c1);
    FA(r[6],r[7],r[8], s2,c2);
    FA(s0,s1,s2, p0,t0);
    FA(c0,c1,c2, t1,t2);
    HA(t0,t1,    p1,t3);
    HA(t2,t3,    p2,p3);
    Planes P; P.p0 = p0; P.p1 = p1; P.p2 = p2; P.p3 = p3; return P;
}

__device__ __forceinline__ u64 spread8(u64 bb) {
    u64 s = (bb * 0x0101010101010101ULL) & 0x8040201008040201ULL;
    return ((s + 0x7f7f7f7f7f7f7f7fULL) >> 7) & 0x0101010101010101ULL;
}

__device__ __forceinline__ u64 vbytes(const Planes& P, int g) {
    int s = 8 * g;
    return  spread8((P.p0 >> s) & 0xFFULL)
         + (spread8((P.p1 >> s) & 0xFFULL) << 1)
         + (spread8((P.p2 >> s) & 0xFFULL) << 2)
         + (spread8((P.p3 >> s) & 0xFFULL) << 3);
}

// ---------------- kernel 3: dense weighted sum ----------------
// w_i = 60*n_i + [n_i==0], n_i = 9x9 box count of E;  out = mean(w*L)
__global__ __launch_bounds__(256)
void final_kernel(const float* __restrict__ L, const u64* __restrict__ eg,
                  u64* __restrict__ acc64, u32* __restrict__ ticket,
                  float* __restrict__ out) {
    __shared__ float sm[256];
    int wi = blockIdx.x * blockDim.x + threadIdx.x;   // word index, 32768 total
    int b  = wi >> 12;                                // 4096 words / image
    int h  = (wi >> 3) & (HH - 1);
    int wc = wi & 7;
    const u64* img = eg + ((size_t)b << 12);

    u64 rows[3][9];
    #pragma unroll
    for (int dh = -4; dh <= 4; ++dh) {
        int hh = h + dh;
        bool okh = (unsigned)hh < (unsigned)HH;
        const u64* rp = img + hh * WPR;
        rows[0][dh + 4] = (okh && wc > 0) ? rp[wc - 1] : 0ULL;
        rows[1][dh + 4] = okh             ? rp[wc]     : 0ULL;
        rows[2][dh + 4] = (okh && wc < 7) ? rp[wc + 1] : 0ULL;
    }
    Planes Pm = vcount9(rows[0]);
    Planes Pc = vcount9(rows[1]);
    Planes Pp = vcount9(rows[2]);

    u64 v[10];
    v[0] = vbytes(Pm, 7);
    #pragma unroll
    for (int g = 0; g < 8; ++g) v[g + 1] = vbytes(Pc, g);
    v[9] = vbytes(Pp, 0);

    const float4* Lr = (const float4*)(L + ((size_t)wi << 6));
    float acc = 0.0f;
    #pragma unroll
    for (int g = 0; g < 8; ++g) {
        u64 a = v[g + 1], lo = v[g], hi = v[g + 2];
        u64 n = a;
        #pragma unroll
        for (int d = 1; d <= 4; ++d) {
            n += (a >> (8 * d)) | (hi << (64 - 8 * d));
            n += (a << (8 * d)) | (lo >> (64 - 8 * d));
        }
        float4 f0 = Lr[2 * g], f1 = Lr[2 * g + 1];
        #pragma unroll
        for (int j = 0; j < 8; ++j) {
            int cnt = (int)((n >> (8 * j)) & 0xFFULL);
            float wgt = cnt ? (float)(60 * cnt) : 1.0f;
            float lv = (j < 4) ? ((j == 0) ? f0.x : (j == 1) ? f0.y : (j == 2) ? f0.z : f0.w)
                               : ((j == 4) ? f1.x : (j == 5) ? f1.y : (j == 6) ? f1.z : f1.w);
            acc += wgt * lv;
        }
    }

    sm[threadIdx.x] = acc;
    __syncthreads();
    for (int s = 128; s > 0; s >>= 1) {
        if (threadIdx.x < s) sm[threadIdx.x] += sm[threadIdx.x + s];
        __syncthreads();
    }
    if (threadIdx.x == 0) {
        u64 vfx = (u64)(long long)llrintf(sm[0] * (float)FPSCALE);
        atomicAdd(acc64, vfx);
        __threadfence();
        u32 t = atomicAdd(ticket, 1u);
        if (t == (u32)(gridDim.x - 1)) {           // last block finishes
            __threadfence();
            u64 total = __hip_atomic_load(acc64, __ATOMIC_RELAXED, __HIP_MEMORY_SCOPE_AGENT);
            out[0] = (float)((double)(long long)total / (FPSCALE * (double)NPIX));
        }
    }
}

extern "C" void kernel_launch(void* const* d_in, const int* in_sizes, int n_in,
                              void* d_out, int out_size, void* d_ws, size_t ws_size,
                              hipStream_t stream) {
    const float* pred = (const float*)d_in[0];
    const int* target = (const int*)d_in[1];
    float* out = (float*)d_out;
    char* ws = (char*)d_ws;

    // ws layout (bytes):
    //   [0,        8388608)  L       float[NPIX]
    //   [8388608,  8650752)  xp      u64[NWORDS]  packed mask
    //   [8650752,  8912896)  eg      u64[NWORDS]  packed endpoints
    //   [8912896,  8912904)  acc64   u64
    //   [8912904,  8912908)  ticket  u32
    float* L    = (float*)(ws);
    u64* xp     = (u64*)(ws + 8388608);
    u64* eg     = (u64*)(ws + 8650752);
    u64* acc64  = (u64*)(ws + 8912896);
    u32* ticket = (u32*)(ws + 8912904);

    prep_kernel<<<dim3(NPIX / 256), dim3(256), 0, stream>>>(pred, target, L, xp, acc64, ticket);
    skel_kernel<<<dim3(BATCH), dim3(256), 0, stream>>>(xp, eg);
    final_kernel<<<dim3(NWORDS / 256), dim3(256), 0, stream>>>(L, eg, acc64, ticket, out);
}

// Round 14
// 58.559 us; speedup vs baseline: 1.0545x; 1.0545x over previous
//
#include <hip/hip_runtime.h>

#define BATCH   8
#define HH      512
#define WW      512
#define IMGPIX  (HH * WW)          // 262144 = 1<<18
#define NPIX    (BATCH * IMGPIX)   // 2097152
#define NWORDS  (NPIX / 64)        // 32768 packed words
#define WPR     8                  // 64-bit words per 512-px row
#define FPSCALE 262144.0           // 2^18 fixed-point scale for i64 reduction
#define MAXPAIR 256

typedef unsigned long long u64;
typedef unsigned int u32;

// ---------------- kernel 1: CE loss + packed binary mask + zero accumulators ----------------
__global__ void prep_kernel(const float* __restrict__ pred, const int* __restrict__ target,
                            float* __restrict__ L, u64* __restrict__ xp,
                            u64* __restrict__ acc64, u32* __restrict__ ticket) {
    int i = blockIdx.x * blockDim.x + threadIdx.x;
    if (i == 0) { acc64[0] = 0ULL; ticket[0] = 0u; }
    if (i >= NPIX) return;
    int b = i >> 18;
    int hw = i & (IMGPIX - 1);
    float p0 = pred[((size_t)(2 * b) << 18) + hw];
    float p1 = pred[((size_t)(2 * b + 1) << 18) + hw];
    // lse = max + log(1 + exp(-|p0-p1|)); fast HW transcendentals (threshold is 1.73 abs)
    float ad = fabsf(p0 - p1);
    float lse = fmaxf(p0, p1) + __logf(1.0f + __expf(-ad));
    int t = target[i];
    L[i] = lse - (t ? p1 : p0);            // -log_softmax[target]
    u64 word = __ballot(p1 > p0);          // 64 consecutive pixels per wave
    if ((threadIdx.x & 63) == 0) xp[i >> 6] = word;
}

// ---------------- bit-sliced helpers ----------------
#define FA(a,b,c,s,cy) { u64 _x = (a)^(b); (s) = _x^(c); (cy) = ((a)&(b)) | ((c)&_x); }
#define HA(a,b,s,cy)   { (s) = (a)^(b); (cy) = (a)&(b); }

// swizzled word index into a [512][8] u64 buffer. Start-bank XOR by (h>>1)&7 spreads the
// even word-stride so b64 accesses stay at the inherent 4-way floor.
__device__ __forceinline__ int sidx(int h, int k) {
    return (h << 3) + (k ^ ((h >> 1) & 7));
}

// load words w0-1 .. w0+4 of row h into A[0..5]; zero outside word range / outside image.
// s and hasRow are wave-uniform -> uniform branches, no divergence.
__device__ __forceinline__ void load6(const u64* __restrict__ B, int h, int s, bool hasRow,
                                      u64* __restrict__ A) {
    if (!hasRow) {
        #pragma unroll
        for (int j = 0; j < 6; ++j) A[j] = 0ULL;
        return;
    }
    if (s == 0) {
        A[0] = 0ULL;
        #pragma unroll
        for (int j = 0; j < 5; ++j) A[j + 1] = B[sidx(h, j)];
    } else {
        #pragma unroll
        for (int j = 0; j < 5; ++j) A[j] = B[sidx(h, 3 + j)];
        A[5] = 0ULL;
    }
}

// ZS delete masks for 4 words (centers Mw[1..4]); neighbor words come from the 6-wide arrays.
template<int FIRST>
__device__ __forceinline__ u64 zs_del4(const u64* __restrict__ Uw, const u64* __restrict__ Mw,
                                       const u64* __restrict__ Dw, u64* __restrict__ dels)
{
    u64 ch = 0;
    #pragma unroll
    for (int k = 0; k < 4; ++k) {
        u64 Mc = Mw[k + 1];
        dels[k] = 0ULL;
        if (Mc == 0ULL) continue;
        u64 Uc = Uw[k + 1], Dc = Dw[k + 1];
        u64 Up = Uw[k],     Mp = Mw[k],     Dp = Dw[k];
        u64 Un = Uw[k + 2], Mn = Mw[k + 2], Dn = Dw[k + 2];
        u64 P2 = Uc, P6 = Dc;
        u64 P3 = (Uc >> 1) | (Un << 63);
        u64 P4 = (Mc >> 1) | (Mn << 63);
        u64 P5 = (Dc >> 1) | (Dn << 63);
        u64 P9 = (Uc << 1) | (Up >> 63);
        u64 P8 = (Mc << 1) | (Mp >> 63);
        u64 P7 = (Dc << 1) | (Dp >> 63);

        u64 sa,ca, sb,cb, sc,cc, b0,cd, sd,ce, b1,cf, b2,b3;
        FA(P2,P3,P4, sa,ca);
        FA(P5,P6,P7, sb,cb);
        FA(P8,P9,sa, sc,cc);
        HA(sb,sc,    b0,cd);
        FA(ca,cb,cc, sd,ce);
        HA(sd,cd,    b1,cf);
        HA(ce,cf,    b2,b3);
        u64 ge2 = b1 | b2 | b3;
        u64 le6 = ~(b3 | (b0 & b1 & b2));

        u64 e, seen, two = 0;
        seen = (~P2) & P3;
        e = (~P3) & P4; two |= seen & e; seen |= e;
        e = (~P4) & P5; two |= seen & e; seen |= e;
        e = (~P5) & P6; two |= seen & e; seen |= e;
        e = (~P6) & P7; two |= seen & e; seen |= e;
        e = (~P7) & P8; two |= seen & e; seen |= e;
        e = (~P8) & P9; two |= seen & e; seen |= e;
        e = (~P9) & P2; two |= seen & e; seen |= e;
        u64 A1 = seen & ~two;

        u64 c34;
        if (FIRST) { u64 t = P4 & P6; c34 = t & (P2 | P8); }
        else       { u64 t = P2 & P8; c34 = t & (P4 | P6); }

        u64 del = Mc & ge2 & le6 & A1 & ~c34;
        dels[k] = del;
        ch |= del;
    }
    return ch;
}

// ---------------- kernel 2: double-buffered skeletonize, half-row per thread ----------------
// 8 blocks x 1024 threads. thread = (row h, half s): owns 4 words w0..w0+3 (w0 = 4s).
// 16 waves/block = 4 waves/SIMD -> LDS latency hides under co-resident waves' VALU.
// 2 barriers per pair; boundary words (partner edge word + neighbor rows) from buf[cur].
__global__ __launch_bounds__(1024)
void skel_kernel(const u64* __restrict__ xp, u64* __restrict__ eg)
{
    __shared__ u64 buf[2][HH * WPR];       // 2 x 32 KB = 64 KB, XOR-swizzled
    const int t  = threadIdx.x;
    const int b  = blockIdx.x;
    const int h  = t & (HH - 1);           // row
    const int s  = t >> 9;                 // half (wave-uniform)
    const int w0 = s << 2;                 // first owned word

    u64 Mw[6], Uw[6], Dw[6], d[4];
    const u64* src = xp + ((size_t)b << 12) + (size_t)h * WPR + w0;
    #pragma unroll
    for (int k = 0; k < 4; ++k) {
        Mw[k + 1] = src[k];
        buf[0][sidx(h, w0 + k)] = Mw[k + 1];
    }
    __syncthreads();

    const bool hasU = (h > 0), hasD = (h < HH - 1);

    for (int p = 0; p < MAXPAIR; ++p) {
        // ---- substep A: read buf0 boundaries, write buf1
        load6(buf[0], h - 1, s, hasU, Uw);
        load6(buf[0], h + 1, s, hasD, Dw);
        Mw[0] = s ? buf[0][sidx(h, 3)] : 0ULL;      // partner edge word (w0-1)
        Mw[5] = s ? 0ULL : buf[0][sidx(h, 4)];      // partner edge word (w0+4)
        u64 chA = zs_del4<1>(Uw, Mw, Dw, d);
        #pragma unroll
        for (int k = 0; k < 4; ++k) {
            Mw[k + 1] ^= d[k];
            buf[1][sidx(h, w0 + k)] = Mw[k + 1];
        }
        __syncthreads();

        // ---- substep B: read buf1 boundaries, write buf0
        load6(buf[1], h - 1, s, hasU, Uw);
        load6(buf[1], h + 1, s, hasD, Dw);
        Mw[0] = s ? buf[1][sidx(h, 3)] : 0ULL;
        Mw[5] = s ? 0ULL : buf[1][sidx(h, 4)];
        u64 chB = zs_del4<0>(Uw, Mw, Dw, d);
        #pragma unroll
        for (int k = 0; k < 4; ++k) {
            Mw[k + 1] ^= d[k];
            buf[0][sidx(h, w0 + k)] = Mw[k + 1];
        }
        if (!__syncthreads_or((chA | chB) != 0ULL)) break; // pair deleted nothing anywhere
    }

    // ---- endpoints E = skel & (exactly one 8-neighbor) for own 4 words
    load6(buf[0], h - 1, s, hasU, Uw);
    load6(buf[0], h + 1, s, hasD, Dw);
    Mw[0] = s ? buf[0][sidx(h, 3)] : 0ULL;
    Mw[5] = s ? 0ULL : buf[0][sidx(h, 4)];
    u64* egr = eg + ((size_t)b << 12) + (size_t)h * WPR + w0;
    #pragma unroll
    for (int k = 0; k < 4; ++k) {
        u64 Mc = Mw[k + 1];
        u64 Uc = Uw[k + 1], Dc = Dw[k + 1];
        u64 Up = Uw[k],     Mp = Mw[k],     Dp = Dw[k];
        u64 Un = Uw[k + 2], Mn = Mw[k + 2], Dn = Dw[k + 2];
        u64 P2 = Uc, P6 = Dc;
        u64 P3 = (Uc >> 1) | (Un << 63);
        u64 P4 = (Mc >> 1) | (Mn << 63);
        u64 P5 = (Dc >> 1) | (Dn << 63);
        u64 P9 = (Uc << 1) | (Up >> 63);
        u64 P8 = (Mc << 1) | (Mp >> 63);
        u64 P7 = (Dc << 1) | (Dp >> 63);
        u64 e, seen, two = 0;
        seen = P2;
        e = P3; two |= seen & e; seen |= e;
        e = P4; two |= seen & e; seen |= e;
        e = P5; two |= seen & e; seen |= e;
        e = P6; two |= seen & e; seen |= e;
        e = P7; two |= seen & e; seen |= e;
        e = P8; two |= seen & e; seen |= e;
        e = P9; two |= seen & e; seen |= e;
        egr[k] = Mc & seen & ~two;             // exactly one neighbor
    }
}

// ---------------- packed 9x9 count helpers ----------------
struct Planes { u64 p0, p1, p2, p3; };

__device__ __forceinline__ Planes vcount9(const u64 r[9]) {
    u64 s0,c0, s1,c1, s2,c2, p0,t0, t1,t2, p1,t3, p2,p3;
    FA(r[0],r[1],r[2], s0,c0);
    FA(r[3],r[4],r[5], s1,c1);
    FA(r[6],r[7],r[8], s2,c2);
    FA(s0,s1,s2, p0,t0);
    FA(c0,c1,c2, t1,t2);
    HA(t0,t1,    p1,t3);
    HA(t2,t3,    p2,p3);
    Planes P; P.p0 = p0; P.p1 = p1; P.p2 = p2; P.p3 = p3; return P;
}

__device__ __forceinline__ u64 spread8(u64 bb) {
    u64 s = (bb * 0x0101010101010101ULL) & 0x8040201008040201ULL;
    return ((s + 0x7f7f7f7f7f7f7f7fULL) >> 7) & 0x0101010101010101ULL;
}

__device__ __forceinline__ u64 vbytes(const Planes& P, int g) {
    int s = 8 * g;
    return  spread8((P.p0 >> s) & 0xFFULL)
         + (spread8((P.p1 >> s) & 0xFFULL) << 1)
         + (spread8((P.p2 >> s) & 0xFFULL) << 2)
         + (spread8((P.p3 >> s) & 0xFFULL) << 3);
}

// ---------------- kernel 3: dense weighted sum ----------------
// w_i = 60*n_i + [n_i==0], n_i = 9x9 box count of E;  out = mean(w*L)
__global__ __launch_bounds__(256)
void final_kernel(const float* __restrict__ L, const u64* __restrict__ eg,
                  u64* __restrict__ acc64, u32* __restrict__ ticket,
                  float* __restrict__ out) {
    __shared__ float sm[256];
    int wi = blockIdx.x * blockDim.x + threadIdx.x;   // word index, 32768 total
    int b  = wi >> 12;                                // 4096 words / image
    int h  = (wi >> 3) & (HH - 1);
    int wc = wi & 7;
    const u64* img = eg + ((size_t)b << 12);

    u64 rows[3][9];
    #pragma unroll
    for (int dh = -4; dh <= 4; ++dh) {
        int hh = h + dh;
        bool okh = (unsigned)hh < (unsigned)HH;
        const u64* rp = img + hh * WPR;
        rows[0][dh + 4] = (okh && wc > 0) ? rp[wc - 1] : 0ULL;
        rows[1][dh + 4] = okh             ? rp[wc]     : 0ULL;
        rows[2][dh + 4] = (okh && wc < 7) ? rp[wc + 1] : 0ULL;
    }
    Planes Pm = vcount9(rows[0]);
    Planes Pc = vcount9(rows[1]);
    Planes Pp = vcount9(rows[2]);

    u64 v[10];
    v[0] = vbytes(Pm, 7);
    #pragma unroll
    for (int g = 0; g < 8; ++g) v[g + 1] = vbytes(Pc, g);
    v[9] = vbytes(Pp, 0);

    const float4* Lr = (const float4*)(L + ((size_t)wi << 6));
    float acc = 0.0f;
    #pragma unroll
    for (int g = 0; g < 8; ++g) {
        u64 a = v[g + 1], lo = v[g], hi = v[g + 2];
        u64 n = a;
        #pragma unroll
        for (int d = 1; d <= 4; ++d) {
            n += (a >> (8 * d)) | (hi << (64 - 8 * d));
            n += (a << (8 * d)) | (lo >> (64 - 8 * d));
        }
        float4 f0 = Lr[2 * g], f1 = Lr[2 * g + 1];
        #pragma unroll
        for (int j = 0; j < 8; ++j) {
            int cnt = (int)((n >> (8 * j)) & 0xFFULL);
            float wgt = cnt ? (float)(60 * cnt) : 1.0f;
            float lv = (j < 4) ? ((j == 0) ? f0.x : (j == 1) ? f0.y : (j == 2) ? f0.z : f0.w)
                               : ((j == 4) ? f1.x : (j == 5) ? f1.y : (j == 6) ? f1.z : f1.w);
            acc += wgt * lv;
        }
    }

    sm[threadIdx.x] = acc;
    __syncthreads();
    for (int s = 128; s > 0; s >>= 1) {
        if (threadIdx.x < s) sm[threadIdx.x] += sm[threadIdx.x + s];
        __syncthreads();
    }
    if (threadIdx.x == 0) {
        u64 vfx = (u64)(long long)llrintf(sm[0] * (float)FPSCALE);
        atomicAdd(acc64, vfx);
        __threadfence();
        u32 t = atomicAdd(ticket, 1u);
        if (t == (u32)(gridDim.x - 1)) {           // last block finishes
            __threadfence();
            u64 total = __hip_atomic_load(acc64, __ATOMIC_RELAXED, __HIP_MEMORY_SCOPE_AGENT);
            out[0] = (float)((double)(long long)total / (FPSCALE * (double)NPIX));
        }
    }
}

extern "C" void kernel_launch(void* const* d_in, const int* in_sizes, int n_in,
                              void* d_out, int out_size, void* d_ws, size_t ws_size,
                              hipStream_t stream) {
    const float* pred = (const float*)d_in[0];
    const int* target = (const int*)d_in[1];
    float* out = (float*)d_out;
    char* ws = (char*)d_ws;

    // ws layout (bytes):
    //   [0,        8388608)  L       float[NPIX]
    //   [8388608,  8650752)  xp      u64[NWORDS]  packed mask
    //   [8650752,  8912896)  eg      u64[NWORDS]  packed endpoints
    //   [8912896,  8912904)  acc64   u64
    //   [8912904,  8912908)  ticket  u32
    float* L    = (float*)(ws);
    u64* xp     = (u64*)(ws + 8388608);
    u64* eg     = (u64*)(ws + 8650752);
    u64* acc64  = (u64*)(ws + 8912896);
    u32* ticket = (u32*)(ws + 8912904);

    prep_kernel<<<dim3(NPIX / 256), dim3(256), 0, stream>>>(pred, target, L, xp, acc64, ticket);
    skel_kernel<<<dim3(BATCH), dim3(1024), 0, stream>>>(xp, eg);
    final_kernel<<<dim3(NWORDS / 256), dim3(256), 0, stream>>>(L, eg, acc64, ticket, out);
}

// Round 15
// 58.195 us; speedup vs baseline: 1.0611x; 1.0063x over previous
//
#include <hip/hip_runtime.h>

#define BATCH   8
#define HH      512
#define WW      512
#define IMGPIX  (HH * WW)          // 262144 = 1<<18
#define NPIX    (BATCH * IMGPIX)   // 2097152
#define NWORDS  (NPIX / 64)        // 32768 packed words
#define WPR     8                  // 64-bit words per 512-px row
#define FPSCALE 262144.0           // 2^18 fixed-point scale for i64 reduction
#define MAXPAIR 256
#define LBLK    504                // L-compute blocks in the fused kernel (total 512)

typedef unsigned long long u64;
typedef unsigned int u32;

// ---------------- kernel 1: packed binary mask only + zero accumulators ----------------
__global__ void prep_xp_kernel(const float* __restrict__ pred, u64* __restrict__ xp,
                               u64* __restrict__ acc64, u32* __restrict__ ticket) {
    int i = blockIdx.x * blockDim.x + threadIdx.x;
    if (i == 0) { acc64[0] = 0ULL; ticket[0] = 0u; }
    if (i >= NPIX) return;
    int b = i >> 18;
    int hw = i & (IMGPIX - 1);
    float p0 = pred[((size_t)(2 * b) << 18) + hw];
    float p1 = pred[((size_t)(2 * b + 1) << 18) + hw];
    u64 word = __ballot(p1 > p0);          // 64 consecutive pixels per wave
    if ((threadIdx.x & 63) == 0) xp[i >> 6] = word;
}

// ---------------- bit-sliced helpers ----------------
#define FA(a,b,c,s,cy) { u64 _x = (a)^(b); (s) = _x^(c); (cy) = ((a)&(b)) | ((c)&_x); }
#define HA(a,b,s,cy)   { (s) = (a)^(b); (cy) = (a)&(b); }

// swizzled word index into a [512][8] u64 buffer. Start-bank XOR by (h>>1)&7 spreads the
// even word-stride so b64 accesses stay at the inherent 4-way floor.
__device__ __forceinline__ int sidx(int h, int k) {
    return (h << 3) + (k ^ ((h >> 1) & 7));
}

// load words w0-1 .. w0+4 of row h into A[0..5]; zero outside word range / outside image.
// s and hasRow are wave-uniform -> uniform branches, no divergence.
__device__ __forceinline__ void load6(const u64* __restrict__ B, int h, int s, bool hasRow,
                                      u64* __restrict__ A) {
    if (!hasRow) {
        #pragma unroll
        for (int j = 0; j < 6; ++j) A[j] = 0ULL;
        return;
    }
    if (s == 0) {
        A[0] = 0ULL;
        #pragma unroll
        for (int j = 0; j < 5; ++j) A[j + 1] = B[sidx(h, j)];
    } else {
        #pragma unroll
        for (int j = 0; j < 5; ++j) A[j] = B[sidx(h, 3 + j)];
        A[5] = 0ULL;
    }
}

// ZS delete masks for 4 words (centers Mw[1..4]); neighbor words come from the 6-wide arrays.
template<int FIRST>
__device__ __forceinline__ u64 zs_del4(const u64* __restrict__ Uw, const u64* __restrict__ Mw,
                                       const u64* __restrict__ Dw, u64* __restrict__ dels)
{
    u64 ch = 0;
    #pragma unroll
    for (int k = 0; k < 4; ++k) {
        u64 Mc = Mw[k + 1];
        dels[k] = 0ULL;
        if (Mc == 0ULL) continue;
        u64 Uc = Uw[k + 1], Dc = Dw[k + 1];
        u64 Up = Uw[k],     Mp = Mw[k],     Dp = Dw[k];
        u64 Un = Uw[k + 2], Mn = Mw[k + 2], Dn = Dw[k + 2];
        u64 P2 = Uc, P6 = Dc;
        u64 P3 = (Uc >> 1) | (Un << 63);
        u64 P4 = (Mc >> 1) | (Mn << 63);
        u64 P5 = (Dc >> 1) | (Dn << 63);
        u64 P9 = (Uc << 1) | (Up >> 63);
        u64 P8 = (Mc << 1) | (Mp >> 63);
        u64 P7 = (Dc << 1) | (Dp >> 63);

        u64 sa,ca, sb,cb, sc,cc, b0,cd, sd,ce, b1,cf, b2,b3;
        FA(P2,P3,P4, sa,ca);
        FA(P5,P6,P7, sb,cb);
        FA(P8,P9,sa, sc,cc);
        HA(sb,sc,    b0,cd);
        FA(ca,cb,cc, sd,ce);
        HA(sd,cd,    b1,cf);
        HA(ce,cf,    b2,b3);
        u64 ge2 = b1 | b2 | b3;
        u64 le6 = ~(b3 | (b0 & b1 & b2));

        u64 e, seen, two = 0;
        seen = (~P2) & P3;
        e = (~P3) & P4; two |= seen & e; seen |= e;
        e = (~P4) & P5; two |= seen & e; seen |= e;
        e = (~P5) & P6; two |= seen & e; seen |= e;
        e = (~P6) & P7; two |= seen & e; seen |= e;
        e = (~P7) & P8; two |= seen & e; seen |= e;
        e = (~P8) & P9; two |= seen & e; seen |= e;
        e = (~P9) & P2; two |= seen & e; seen |= e;
        u64 A1 = seen & ~two;

        u64 c34;
        if (FIRST) { u64 t = P4 & P6; c34 = t & (P2 | P8); }
        else       { u64 t = P2 & P8; c34 = t & (P4 | P6); }

        u64 del = Mc & ge2 & le6 & A1 & ~c34;
        dels[k] = del;
        ch |= del;
    }
    return ch;
}

// ---------------- kernel 2: fused {8 skeleton blocks} + {504 L-compute blocks} ----------------
// Blocks 0..7: R13 half-row skeleton (1024 thr, 16 waves, 64 KB LDS, 2 barriers/pair).
// Blocks 8..511: cross-entropy L map on the otherwise-idle CUs — 25 MB of HBM traffic
// hidden under the skeleton's ~38 us serial chain. Block-uniform branch; barriers only
// in skel blocks (per-block semantics -> legal).
__global__ __launch_bounds__(1024)
void skel_plus_L_kernel(const u64* __restrict__ xp, u64* __restrict__ eg,
                        const float* __restrict__ pred, const int* __restrict__ target,
                        float* __restrict__ L)
{
    __shared__ u64 buf[2][HH * WPR];       // 64 KB (skel blocks only; caps at 2 blocks/CU)

    if (blockIdx.x >= BATCH) {
        // ---------- L-compute path ----------
        int idx = (blockIdx.x - BATCH) * 1024 + threadIdx.x;
        const int stride = LBLK * 1024;
        for (int i = idx; i < NPIX; i += stride) {
            int b = i >> 18;
            int hw = i & (IMGPIX - 1);
            float p0 = pred[((size_t)(2 * b) << 18) + hw];
            float p1 = pred[((size_t)(2 * b + 1) << 18) + hw];
            // lse = max + log(1 + exp(-|p0-p1|)); fast HW transcendentals (abs threshold 1.73)
            float ad = fabsf(p0 - p1);
            float lse = fmaxf(p0, p1) + __logf(1.0f + __expf(-ad));
            int t = target[i];
            L[i] = lse - (t ? p1 : p0);    // -log_softmax[target]
        }
        return;
    }

    // ---------- skeleton path (R13) ----------
    const int t  = threadIdx.x;
    const int b  = blockIdx.x;
    const int h  = t & (HH - 1);           // row
    const int s  = t >> 9;                 // half (wave-uniform)
    const int w0 = s << 2;                 // first owned word

    u64 Mw[6], Uw[6], Dw[6], d[4];
    const u64* src = xp + ((size_t)b << 12) + (size_t)h * WPR + w0;
    #pragma unroll
    for (int k = 0; k < 4; ++k) {
        Mw[k + 1] = src[k];
        buf[0][sidx(h, w0 + k)] = Mw[k + 1];
    }
    __syncthreads();

    const bool hasU = (h > 0), hasD = (h < HH - 1);

    for (int p = 0; p < MAXPAIR; ++p) {
        // ---- substep A: read buf0 boundaries, write buf1
        load6(buf[0], h - 1, s, hasU, Uw);
        load6(buf[0], h + 1, s, hasD, Dw);
        Mw[0] = s ? buf[0][sidx(h, 3)] : 0ULL;      // partner edge word (w0-1)
        Mw[5] = s ? 0ULL : buf[0][sidx(h, 4)];      // partner edge word (w0+4)
        u64 chA = zs_del4<1>(Uw, Mw, Dw, d);
        #pragma unroll
        for (int k = 0; k < 4; ++k) {
            Mw[k + 1] ^= d[k];
            buf[1][sidx(h, w0 + k)] = Mw[k + 1];
        }
        __syncthreads();

        // ---- substep B: read buf1 boundaries, write buf0
        load6(buf[1], h - 1, s, hasU, Uw);
        load6(buf[1], h + 1, s, hasD, Dw);
        Mw[0] = s ? buf[1][sidx(h, 3)] : 0ULL;
        Mw[5] = s ? 0ULL : buf[1][sidx(h, 4)];
        u64 chB = zs_del4<0>(Uw, Mw, Dw, d);
        #pragma unroll
        for (int k = 0; k < 4; ++k) {
            Mw[k + 1] ^= d[k];
            buf[0][sidx(h, w0 + k)] = Mw[k + 1];
        }
        if (!__syncthreads_or((chA | chB) != 0ULL)) break; // pair deleted nothing anywhere
    }

    // ---- endpoints E = skel & (exactly one 8-neighbor) for own 4 words
    load6(buf[0], h - 1, s, hasU, Uw);
    load6(buf[0], h + 1, s, hasD, Dw);
    Mw[0] = s ? buf[0][sidx(h, 3)] : 0ULL;
    Mw[5] = s ? 0ULL : buf[0][sidx(h, 4)];
    u64* egr = eg + ((size_t)b << 12) + (size_t)h * WPR + w0;
    #pragma unroll
    for (int k = 0; k < 4; ++k) {
        u64 Mc = Mw[k + 1];
        u64 Uc = Uw[k + 1], Dc = Dw[k + 1];
        u64 Up = Uw[k],     Mp = Mw[k],     Dp = Dw[k];
        u64 Un = Uw[k + 2], Mn = Mw[k + 2], Dn = Dw[k + 2];
        u64 P2 = Uc, P6 = Dc;
        u64 P3 = (Uc >> 1) | (Un << 63);
        u64 P4 = (Mc >> 1) | (Mn << 63);
        u64 P5 = (Dc >> 1) | (Dn << 63);
        u64 P9 = (Uc << 1) | (Up >> 63);
        u64 P8 = (Mc << 1) | (Mp >> 63);
        u64 P7 = (Dc << 1) | (Dp >> 63);
        u64 e, seen, two = 0;
        seen = P2;
        e = P3; two |= seen & e; seen |= e;
        e = P4; two |= seen & e; seen |= e;
        e = P5; two |= seen & e; seen |= e;
        e = P6; two |= seen & e; seen |= e;
        e = P7; two |= seen & e; seen |= e;
        e = P8; two |= seen & e; seen |= e;
        e = P9; two |= seen & e; seen |= e;
        egr[k] = Mc & seen & ~two;             // exactly one neighbor
    }
}

// ---------------- packed 9x9 count helpers ----------------
struct Planes { u64 p0, p1, p2, p3; };

__device__ __forceinline__ Planes vcount9(const u64 r[9]) {
    u64 s0,c0, s1,c1, s2,c2, p0,t0, t1,t2, p1,t3, p2,p3;
    FA(r[0],r[1],r[2], s0,c0);
    FA(r[3],r[4],r[5], s1,c1);
    FA(r[6],r[7],r[8], s2,c2);
    FA(s0,s1,s2, p0,t0);
    FA(c0,c1,c2, t1,t2);
    HA(t0,t1,    p1,t3);
    HA(t2,t3,    p2,p3);
    Planes P; P.p0 = p0; P.p1 = p1; P.p2 = p2; P.p3 = p3; return P;
}

__device__ __forceinline__ u64 spread8(u64 bb) {
    u64 s = (bb * 0x0101010101010101ULL) & 0x8040201008040201ULL;
    return ((s + 0x7f7f7f7f7f7f7f7fULL) >> 7) & 0x0101010101010101ULL;
}

__device__ __forceinline__ u64 vbytes(const Planes& P, int g) {
    int s = 8 * g;
    return  spread8((P.p0 >> s) & 0xFFULL)
         + (spread8((P.p1 >> s) & 0xFFULL) << 1)
         + (spread8((P.p2 >> s) & 0xFFULL) << 2)
         + (spread8((P.p3 >> s) & 0xFFULL) << 3);
}

// ---------------- kernel 3: dense weighted sum ----------------
// w_i = 60*n_i + [n_i==0], n_i = 9x9 box count of E;  out = mean(w*L)
__global__ __launch_bounds__(256)
void final_kernel(const float* __restrict__ L, const u64* __restrict__ eg,
                  u64* __restrict__ acc64, u32* __restrict__ ticket,
                  float* __restrict__ out) {
    __shared__ float sm[256];
    int wi = blockIdx.x * blockDim.x + threadIdx.x;   // word index, 32768 total
    int b  = wi >> 12;                                // 4096 words / image
    int h  = (wi >> 3) & (HH - 1);
    int wc = wi & 7;
    const u64* img = eg + ((size_t)b << 12);

    u64 rows[3][9];
    #pragma unroll
    for (int dh = -4; dh <= 4; ++dh) {
        int hh = h + dh;
        bool okh = (unsigned)hh < (unsigned)HH;
        const u64* rp = img + hh * WPR;
        rows[0][dh + 4] = (okh && wc > 0) ? rp[wc - 1] : 0ULL;
        rows[1][dh + 4] = okh             ? rp[wc]     : 0ULL;
        rows[2][dh + 4] = (okh && wc < 7) ? rp[wc + 1] : 0ULL;
    }
    Planes Pm = vcount9(rows[0]);
    Planes Pc = vcount9(rows[1]);
    Planes Pp = vcount9(rows[2]);

    u64 v[10];
    v[0] = vbytes(Pm, 7);
    #pragma unroll
    for (int g = 0; g < 8; ++g) v[g + 1] = vbytes(Pc, g);
    v[9] = vbytes(Pp, 0);

    const float4* Lr = (const float4*)(L + ((size_t)wi << 6));
    float acc = 0.0f;
    #pragma unroll
    for (int g = 0; g < 8; ++g) {
        u64 a = v[g + 1], lo = v[g], hi = v[g + 2];
        u64 n = a;
        #pragma unroll
        for (int d = 1; d <= 4; ++d) {
            n += (a >> (8 * d)) | (hi << (64 - 8 * d));
            n += (a << (8 * d)) | (lo >> (64 - 8 * d));
        }
        float4 f0 = Lr[2 * g], f1 = Lr[2 * g + 1];
        #pragma unroll
        for (int j = 0; j < 8; ++j) {
            int cnt = (int)((n >> (8 * j)) & 0xFFULL);
            float wgt = cnt ? (float)(60 * cnt) : 1.0f;
            float lv = (j < 4) ? ((j == 0) ? f0.x : (j == 1) ? f0.y : (j == 2) ? f0.z : f0.w)
                               : ((j == 4) ? f1.x : (j == 5) ? f1.y : (j == 6) ? f1.z : f1.w);
            acc += wgt * lv;
        }
    }

    sm[threadIdx.x] = acc;
    __syncthreads();
    for (int s = 128; s > 0; s >>= 1) {
        if (threadIdx.x < s) sm[threadIdx.x] += sm[threadIdx.x + s];
        __syncthreads();
    }
    if (threadIdx.x == 0) {
        u64 vfx = (u64)(long long)llrintf(sm[0] * (float)FPSCALE);
        atomicAdd(acc64, vfx);
        __threadfence();
        u32 t = atomicAdd(ticket, 1u);
        if (t == (u32)(gridDim.x - 1)) {           // last block finishes
            __threadfence();
            u64 total = __hip_atomic_load(acc64, __ATOMIC_RELAXED, __HIP_MEMORY_SCOPE_AGENT);
            out[0] = (float)((double)(long long)total / (FPSCALE * (double)NPIX));
        }
    }
}

extern "C" void kernel_launch(void* const* d_in, const int* in_sizes, int n_in,
                              void* d_out, int out_size, void* d_ws, size_t ws_size,
                              hipStream_t stream) {
    const float* pred = (const float*)d_in[0];
    const int* target = (const int*)d_in[1];
    float* out = (float*)d_out;
    char* ws = (char*)d_ws;

    // ws layout (bytes):
    //   [0,        8388608)  L       float[NPIX]
    //   [8388608,  8650752)  xp      u64[NWORDS]  packed mask
    //   [8650752,  8912896)  eg      u64[NWORDS]  packed endpoints
    //   [8912896,  8912904)  acc64   u64
    //   [8912904,  8912908)  ticket  u32
    float* L    = (float*)(ws);
    u64* xp     = (u64*)(ws + 8388608);
    u64* eg     = (u64*)(ws + 8650752);
    u64* acc64  = (u64*)(ws + 8912896);
    u32* ticket = (u32*)(ws + 8912904);

    prep_xp_kernel<<<dim3(NPIX / 256), dim3(256), 0, stream>>>(pred, xp, acc64, ticket);
    skel_plus_L_kernel<<<dim3(BATCH + LBLK), dim3(1024), 0, stream>>>(xp, eg, pred, target, L);
    final_kernel<<<dim3(NWORDS / 256), dim3(256), 0, stream>>>(L, eg, acc64, ticket, out);
}